// Round 5
// baseline (358.382 us; speedup 1.0000x reference)
//
#include <hip/hip_runtime.h>
#include <math.h>

#define BSZ 32
#define CH  256

typedef short  bf16x8 __attribute__((ext_vector_type(8)));
typedef float  f32x4  __attribute__((ext_vector_type(4)));
typedef unsigned short ushort_t;
typedef unsigned int   uint_t;

#define MFMA(a, b, c) __builtin_amdgcn_mfma_f32_16x16x32_bf16((a), (b), (c), 0, 0, 0)

__device__ __forceinline__ ushort_t f2b(float f) {
    uint_t u = __builtin_bit_cast(uint_t, f);
    uint_t r = (u + 0x7FFFu + ((u >> 16) & 1u)) >> 16;   // RTNE
    return (ushort_t)r;
}
__device__ __forceinline__ float b2f(ushort_t u) {
    uint_t v = ((uint_t)u) << 16;
    return __builtin_bit_cast(float, v);
}
__device__ __forceinline__ uint_t pk2(float a, float b) {
    return (uint_t)f2b(a) | ((uint_t)f2b(b) << 16);
}
__device__ __forceinline__ bf16x8 u4b8(uint4 u) {
    return __builtin_bit_cast(bf16x8, u);
}

// ---------------- kernel 1: per-cell winning edge (last write wins) -------
__global__ void edge_win_kernel(const int* __restrict__ ei, int E, int nb,
                                int* __restrict__ win) {
    int e = blockIdx.x * blockDim.x + threadIdx.x;
    if (e >= E) return;
    int r = ei[e];
    int c = ei[E + e];
    int br = r >> 5, bc = c >> 5;
    if (br == bc && br < nb) {
        atomicMax(&win[br * (BSZ * BSZ) + (r & 31) * BSZ + (c & 31)], e);
    }
}

// ---------------- kernel 1b: winning edges scatter their features ---------
// cellinfo[cell] = 4 bf16 {dx,dy,dz,val}; non-winners stay 0xFFFF (NaN).
__global__ void edge_feat_kernel(const int* __restrict__ ei,
                                 const float* __restrict__ ev,
                                 const float* __restrict__ pos,
                                 const int* __restrict__ win, int E,
                                 ushort_t* __restrict__ cellinfo) {
    int e = blockIdx.x * blockDim.x + threadIdx.x;
    if (e >= E) return;
    int r = ei[e];
    int c = ei[E + e];
    int br = r >> 5, bc = c >> 5;
    if (br != bc) return;
    int cell = br * 1024 + (r & 31) * 32 + (c & 31);
    if (win[cell] != e) return;
    float d0 = pos[c * 3 + 0] - pos[r * 3 + 0];
    float d1 = pos[c * 3 + 1] - pos[r * 3 + 1];
    float d2 = pos[c * 3 + 2] - pos[r * 3 + 2];
    float d3 = ev[e];
    uint2 w; w.x = pk2(d0, d1); w.y = pk2(d2, d3);
    *(uint2*)&cellinfo[(size_t)cell * 4] = w;
}

// ---------------- kernel 2: fp32 -> bf16 weight conversion ----------------
__global__ void wconv_kernel(const float* __restrict__ qkv_w,
                             const float* __restrict__ proj_w,
                             ushort_t* __restrict__ qkv_wb,
                             ushort_t* __restrict__ proj_wb) {
    int i = blockIdx.x * blockDim.x + threadIdx.x;
    if (i < 768 * 256) qkv_wb[i] = f2b(qkv_w[i]);
    if (i < 256 * 256) proj_wb[i] = f2b(proj_w[i]);
}

// ---------------- kernel 3: qkv GEMM, BM=128, 512 threads (8 waves) -------
// q,k -> leaf-chunked fragment layout in d_out (bf16):
//   addr(ushort) = g*16384 + lc*256 + lane*4,  lc = tt*2 + (row>>4)
// v -> vT[g][ch][32] via swapped MFMA orientation. Means via shfl reduce.
__global__ __launch_bounds__(512, 4)
void qkv_gemm(const float* __restrict__ x,
              const ushort_t* __restrict__ wb,
              const float* __restrict__ bias,
              ushort_t* qk,
              ushort_t* __restrict__ vT,
              float* __restrict__ krow,
              float* __restrict__ vrow)
{
    __shared__ ushort_t xb[128 * 256];   // 64 KiB
    const int t = threadIdx.x;
    const int wid = t >> 6, lane = t & 63, l15 = lane & 15, lg = lane >> 4;
    const int bi = blockIdx.x, mbase = bi * 128;

    // stage x tile -> bf16 LDS (coalesced)
    #pragma unroll 8
    for (int i = 0; i < 16; ++i) {
        int flat = i * 2048 + t * 4;
        int r = flat >> 8, c = flat & 255;
        float4 xv = *(const float4*)&x[(size_t)(mbase + r) * CH + c];
        uint2 w; w.x = pk2(xv.x, xv.y); w.y = pk2(xv.z, xv.w);
        *(uint2*)&xb[r * 256 + (c ^ ((r & 7) << 3))] = w;
    }
    __syncthreads();

    const int slB = (l15 & 7) << 3;
    for (int mt = 0; mt < 6; ++mt) {
        int tt = mt * 8 + wid;               // ch-tile 0..47
        const ushort_t* wrow = wb + (size_t)(tt * 16 + l15) * 256 + lg * 8;
        bf16x8 wf[8];
        #pragma unroll
        for (int ks = 0; ks < 8; ++ks) wf[ks] = *(const bf16x8*)(wrow + ks * 32);
        f32x4 acc[8];
        #pragma unroll
        for (int m = 0; m < 8; ++m) acc[m] = (f32x4){0.f, 0.f, 0.f, 0.f};

        if (tt < 32) {
            // q/k: swapped (A=W rows, B=x rows) -> D[ch][row]
            #pragma unroll
            for (int ks = 0; ks < 8; ++ks) {
                int k0 = (ks * 32 + lg * 8) ^ slB;
                #pragma unroll
                for (int m = 0; m < 8; ++m) {
                    bf16x8 xf = *(const bf16x8*)&xb[(m * 16 + l15) * 256 + k0];
                    acc[m] = MFMA(wf[ks], xf, acc[m]);
                }
            }
            f32x4 bv4 = *(const f32x4*)&bias[tt * 16 + lg * 4];
            #pragma unroll
            for (int m = 0; m < 8; ++m) {
                f32x4 v = acc[m] + bv4;
                uint2 w; w.x = pk2(v[0], v[1]); w.y = pk2(v[2], v[3]);
                int g = bi * 4 + (m >> 1), lc = tt * 2 + (m & 1);
                *(uint2*)&qk[(size_t)g * 16384 + lc * 256 + lane * 4] = w;
            }
            if (tt >= 16) {                  // k block-means
                #pragma unroll
                for (int g = 0; g < 4; ++g) {
                    #pragma unroll
                    for (int j = 0; j < 4; ++j) {
                        float s = acc[2 * g][j] + acc[2 * g + 1][j];
                        s += __shfl_xor(s, 1);
                        s += __shfl_xor(s, 2);
                        s += __shfl_xor(s, 4);
                        s += __shfl_xor(s, 8);
                        if (l15 == 0)
                            krow[(bi * 4 + g) * 256 + (tt - 16) * 16 + lg * 4 + j]
                                = s * 0.03125f + bv4[j];
                    }
                }
            }
        } else {
            // v: non-swapped (A=x rows, B=W rows) -> D[row][ch] (transposed)
            #pragma unroll
            for (int ks = 0; ks < 8; ++ks) {
                int k0 = (ks * 32 + lg * 8) ^ slB;
                #pragma unroll
                for (int m = 0; m < 8; ++m) {
                    bf16x8 xf = *(const bf16x8*)&xb[(m * 16 + l15) * 256 + k0];
                    acc[m] = MFMA(xf, wf[ks], acc[m]);
                }
            }
            int vch = (tt - 32) * 16 + l15;
            float bv = bias[512 + vch];
            #pragma unroll
            for (int m = 0; m < 8; ++m) {
                f32x4 v = acc[m];
                uint2 w; w.x = pk2(v[0] + bv, v[1] + bv);
                w.y = pk2(v[2] + bv, v[3] + bv);
                int g = bi * 4 + (m >> 1);
                *(uint2*)&vT[(size_t)g * 8192 + vch * 32 + (m & 1) * 16 + lg * 4] = w;
            }
            #pragma unroll
            for (int g = 0; g < 4; ++g) {    // v block-means
                float s = acc[2*g][0] + acc[2*g][1] + acc[2*g][2] + acc[2*g][3]
                        + acc[2*g+1][0] + acc[2*g+1][1] + acc[2*g+1][2] + acc[2*g+1][3];
                s += __shfl_xor(s, 16);
                s += __shfl_xor(s, 32);
                if (lg == 0)
                    vrow[(bi * 4 + g) * 256 + vch] = s * 0.03125f + bv;
            }
        }
    }
}

// ---------------- kernel 4: attention + proj per leaf block ---------------
// LDS 25,088 B -> 6 blocks/CU. comb/comb32 are wave-private (no barrier);
// single __syncthreads() before proj (cross-wave xo).
#define L_XO     0        // bf16 [32 qi][256 c swz]             16384 B
#define L_COMB   16384    // bf16 [4h][32 qi][32 kj swz]          8192 B
#define L_COMB32 24576    // f32 [4h][32 qi]                       512 B
#define L_TOTAL  25088

__global__ __launch_bounds__(256, 6)
void leaf_attn(const ushort_t* qk,            // aliases out (bf16 view)
               const ushort_t* __restrict__ vT,
               const float* __restrict__ krow,
               const float* __restrict__ vrow,
               const ushort_t* __restrict__ cellinfo,
               const ushort_t* __restrict__ proj_wb,
               const float* __restrict__ proj_b,
               const float* __restrict__ gate_w,
               const float* __restrict__ gate_b,
               float* out)
{
    __shared__ __align__(16) char smem[L_TOTAL];
    ushort_t* xo     = (ushort_t*)(smem + L_XO);
    ushort_t* comb   = (ushort_t*)(smem + L_COMB);
    float*    comb32 = (float*)(smem + L_COMB32);

    const int b = blockIdx.x, t = threadIdx.x;
    const int h = t >> 6, lane = t & 63, l15 = lane & 15, lg = lane >> 4;
    const int base = b * BSZ;
    const ushort_t* qkb = qk + (size_t)b * 16384;

    // ---- direct fragment loads (all coalesced / L2-friendly) ------------
    uint4 qld[2][2], kld[2][2];              // [row-tile][ks]
    #pragma unroll
    for (int rt = 0; rt < 2; ++rt) {
        #pragma unroll
        for (int ks = 0; ks < 2; ++ks) {
            int ttq = h * 4 + ks * 2 + (lg >> 1);
            int a0 = (ttq * 2 + rt) * 256 + ((lg & 1) * 32 + l15) * 4;
            uint2 u0 = *(const uint2*)&qkb[a0];
            uint2 u1 = *(const uint2*)&qkb[a0 + 64];
            qld[rt][ks] = (uint4){u0.x, u0.y, u1.x, u1.y};
            int b0 = ((ttq + 16) * 2 + rt) * 256 + ((lg & 1) * 32 + l15) * 4;
            uint2 w0 = *(const uint2*)&qkb[b0];
            uint2 w1 = *(const uint2*)&qkb[b0 + 64];
            kld[rt][ks] = (uint4){w0.x, w0.y, w1.x, w1.y};
        }
    }
    bf16x8 vf[4];                            // PV A-frags (vT direct)
    #pragma unroll
    for (int ct = 0; ct < 4; ++ct)
        vf[ct] = *(const bf16x8*)&vT[(size_t)b * 8192
                                     + (h * 64 + ct * 16 + l15) * 32 + lg * 8];
    bf16x8 kr2[2];                           // k-mean row as sparse A-frag
    #pragma unroll
    for (int ks = 0; ks < 2; ++ks) {
        uint4 u = {0u, 0u, 0u, 0u};
        if (l15 == 0) {
            const float* kp = &krow[b * 256 + h * 64 + ks * 32 + lg * 8];
            u.x = pk2(kp[0], kp[1]); u.y = pk2(kp[2], kp[3]);
            u.z = pk2(kp[4], kp[5]); u.w = pk2(kp[6], kp[7]);
        }
        kr2[ks] = u4b8(u);
    }
    const float gw0 = gate_w[h * 4 + 0], gw1 = gate_w[h * 4 + 1];
    const float gw2 = gate_w[h * 4 + 2], gw3 = gate_w[h * 4 + 3];
    const float gb  = gate_b[h];

    // ---- scores MFMA: A=k (M=kj), B=q (N=qi) -> D[kj][qi] ---------------
    f32x4 s[2][2], s2[2];
    #pragma unroll
    for (int qt = 0; qt < 2; ++qt) {
        s[qt][0] = (f32x4){0.f,0.f,0.f,0.f};
        s[qt][1] = (f32x4){0.f,0.f,0.f,0.f};
        s2[qt]   = (f32x4){0.f,0.f,0.f,0.f};
    }
    #pragma unroll
    for (int qt = 0; qt < 2; ++qt) {
        #pragma unroll
        for (int ks = 0; ks < 2; ++ks) {
            bf16x8 qf = u4b8(qld[qt][ks]);
            #pragma unroll
            for (int kt = 0; kt < 2; ++kt)
                s[qt][kt] = MFMA(u4b8(kld[kt][ks]), qf, s[qt][kt]);
            s2[qt] = MFMA(kr2[ks], qf, s2[qt]);
        }
    }

    // ---- softmax + gate in-register via cellinfo fragments --------------
    const ushort_t* crow = cellinfo + (size_t)b * 4096;   // 1024 cells * 4
    #pragma unroll
    for (int qt = 0; qt < 2; ++qt) {
        int qi = qt * 16 + l15;
        float r[8], gt[8];
        #pragma unroll
        for (int kt = 0; kt < 2; ++kt) {
            int kj0 = kt * 16 + lg * 4;
            const uint_t* cp = (const uint_t*)(crow + ((size_t)qi * 32 + kj0) * 4);
            uint4 cA = *(const uint4*)cp;        // cells j=0,1
            uint4 cB = *(const uint4*)(cp + 4);  // cells j=2,3
            uint_t d01[4] = {cA.x, cA.z, cB.x, cB.z};
            uint_t d23[4] = {cA.y, cA.w, cB.y, cB.w};
            #pragma unroll
            for (int j = 0; j < 4; ++j) {
                int kj = kj0 + j;
                bool fixed = (kj == qi);
                ushort_t e3b = (ushort_t)(d23[j] >> 16);
                bool valid = (e3b != (ushort_t)0xFFFFu);
                float e3 = b2f(e3b);
                float sb = fixed ? 1.0f : (valid ? e3 : -INFINITY);
                float g;
                if (fixed)      g = gw3 + gb;
                else if (valid) g = b2f((ushort_t)(d01[j] & 0xFFFF)) * gw0
                                  + b2f((ushort_t)(d01[j] >> 16))    * gw1
                                  + b2f((ushort_t)(d23[j] & 0xFFFF)) * gw2
                                  + e3 * gw3 + gb;
                else            g = 0.0f;
                r[kt * 4 + j]  = s[qt][kt][j] * 0.125f + sb;
                gt[kt * 4 + j] = g;
            }
        }
        float r2 = s2[qt][0] * 0.125f + 1.0f;      // valid on lg==0 (kj=32)
        float m = fmaxf(fmaxf(fmaxf(r[0], r[1]), fmaxf(r[2], r[3])),
                        fmaxf(fmaxf(r[4], r[5]), fmaxf(r[6], r[7])));
        if (lg == 0) m = fmaxf(m, r2);
        m = fmaxf(m, __shfl_xor(m, 16));
        m = fmaxf(m, __shfl_xor(m, 32));
        float sum = 0.f;
        #pragma unroll
        for (int i = 0; i < 8; ++i) { r[i] = __expf(r[i] - m); sum += r[i]; }
        float e2 = (lg == 0) ? __expf(r2 - m) : 0.f;
        sum += e2;
        sum += __shfl_xor(sum, 16);
        sum += __shfl_xor(sum, 32);
        float inv = 1.0f / sum;
        int swz = (l15 >> 2) << 3;
        #pragma unroll
        for (int kt = 0; kt < 2; ++kt) {
            int kj0 = kt * 16 + lg * 4;
            uint2 w;
            w.x = pk2(r[kt*4+0] * inv + gt[kt*4+0], r[kt*4+1] * inv + gt[kt*4+1]);
            w.y = pk2(r[kt*4+2] * inv + gt[kt*4+2], r[kt*4+3] * inv + gt[kt*4+3]);
            *(uint2*)&comb[(h * 32 + qi) * 32 + (kj0 ^ swz)] = w;
        }
        if (lg == 0)
            comb32[h * 32 + qi] = e2 * inv + (gw3 + gb);
    }
    // comb/comb32 are wave-private (head h) -> no __syncthreads needed.

    // ---- PV MFMA: A=vT (M=c), B=comb (N=qi) -> D[c][qi] + fixup ---------
    bf16x8 cfr[2];
    float c32[2];
    #pragma unroll
    for (int qt = 0; qt < 2; ++qt) {
        int qi = qt * 16 + l15;
        int off = (lg * 8) ^ (((l15 >> 2) & 3) << 3);
        cfr[qt] = *(const bf16x8*)&comb[(h * 32 + qi) * 32 + off];
        c32[qt] = comb32[h * 32 + qi];
    }
    f32x4 vr[4];
    #pragma unroll
    for (int ct = 0; ct < 4; ++ct)
        vr[ct] = *(const f32x4*)&vrow[b * 256 + h * 64 + ct * 16 + lg * 4];

    #pragma unroll
    for (int ct = 0; ct < 4; ++ct) {
        #pragma unroll
        for (int qt = 0; qt < 2; ++qt) {
            f32x4 acc = {0.f, 0.f, 0.f, 0.f};
            acc = MFMA(vf[ct], cfr[qt], acc);
            int qi = qt * 16 + l15;
            float c2 = c32[qt];
            uint2 w;
            w.x = pk2(acc[0] + c2 * vr[ct][0], acc[1] + c2 * vr[ct][1]);
            w.y = pk2(acc[2] + c2 * vr[ct][2], acc[3] + c2 * vr[ct][3]);
            int c0 = h * 64 + ct * 16 + lg * 4;
            *(uint2*)&xo[qi * 256 + (c0 ^ ((l15 & 7) << 3))] = w;
        }
    }
    __syncthreads();   // the only barrier: xo is read cross-wave by proj

    // ---- proj MFMA (swapped) + fp32 out store ---------------------------
    {
        const int slR = (l15 & 7) << 3;
        #pragma unroll
        for (int mt = 0; mt < 4; ++mt) {
            int n0 = h * 64 + mt * 16;
            const ushort_t* arow = proj_wb + (size_t)(n0 + l15) * 256 + lg * 8;
            f32x4 acc0 = {0.f, 0.f, 0.f, 0.f};
            f32x4 acc1 = {0.f, 0.f, 0.f, 0.f};
            #pragma unroll
            for (int ks = 0; ks < 8; ++ks) {
                bf16x8 a  = *(const bf16x8*)(arow + ks * 32);
                int k0 = ks * 32 + lg * 8;
                bf16x8 b0 = *(const bf16x8*)&xo[l15 * 256 + (k0 ^ slR)];
                bf16x8 b1 = *(const bf16x8*)&xo[(16 + l15) * 256 + (k0 ^ slR)];
                acc0 = MFMA(a, b0, acc0);
                acc1 = MFMA(a, b1, acc1);
            }
            f32x4 bv = *(const f32x4*)(proj_b + n0 + lg * 4);
            acc0 += bv; acc1 += bv;
            int c0 = n0 + lg * 4;
            *(f32x4*)(out + (size_t)(base + l15) * 256 + c0)      = acc0;
            *(f32x4*)(out + (size_t)(base + 16 + l15) * 256 + c0) = acc1;
        }
    }
}

extern "C" void kernel_launch(void* const* d_in, const int* in_sizes, int n_in,
                              void* d_out, int out_size, void* d_ws, size_t ws_size,
                              hipStream_t stream) {
    const float* x      = (const float*)d_in[0];
    const int*   ei     = (const int*)  d_in[1];
    const float* ev     = (const float*)d_in[2];
    const float* pos    = (const float*)d_in[3];
    const float* qkv_w  = (const float*)d_in[4];
    const float* qkv_b  = (const float*)d_in[5];
    const float* proj_w = (const float*)d_in[6];
    const float* proj_b = (const float*)d_in[7];
    const float* gate_w = (const float*)d_in[8];
    const float* gate_b = (const float*)d_in[9];
    float* out = (float*)d_out;

    const int E  = in_sizes[2];
    const int N  = in_sizes[0] / CH;
    const int nb = N / BSZ;

    char* ws = (char*)d_ws;
    int*      win      = (int*)ws;                              // nb*4096 B
    ushort_t* cellinfo = (ushort_t*)(ws + (size_t)nb * 4096);   // nb*8192 B
    size_t off = (size_t)nb * 12288;
    ushort_t* qkv_wb  = (ushort_t*)(ws + off); off += 768 * 256 * 2;
    ushort_t* proj_wb = (ushort_t*)(ws + off); off += 256 * 256 * 2;
    float*    krow    = (float*)(ws + off);    off += (size_t)nb * 1024;
    float*    vrow    = (float*)(ws + off);    off += (size_t)nb * 1024;
    ushort_t* vT      = (ushort_t*)(ws + off); off += (size_t)nb * 16384;
    ushort_t* qk      = (ushort_t*)d_out;               // d_out as bf16 scratch

    // one memset covers win (-1) and cellinfo (NaN sentinel) — both 0xFF
    hipMemsetAsync(ws, 0xFF, (size_t)nb * 12288, stream);
    edge_win_kernel<<<(E + 255) / 256, 256, 0, stream>>>(ei, E, nb, win);
    edge_feat_kernel<<<(E + 255) / 256, 256, 0, stream>>>(ei, ev, pos, win, E,
                                                          cellinfo);
    wconv_kernel<<<768, 256, 0, stream>>>(qkv_w, proj_w, qkv_wb, proj_wb);
    qkv_gemm<<<nb / 4, 512, 0, stream>>>(x, qkv_wb, qkv_b, qk, vT, krow, vrow);
    leaf_attn<<<nb, 256, 0, stream>>>(qk, vT, krow, vrow, cellinfo,
                                      proj_wb, proj_b, gate_w, gate_b, out);
}

// Round 6
// 329.774 us; speedup vs baseline: 1.0868x; 1.0868x over previous
//
#include <hip/hip_runtime.h>
#include <math.h>

#define BSZ 32
#define CH  256

typedef short  bf16x8 __attribute__((ext_vector_type(8)));
typedef float  f32x4  __attribute__((ext_vector_type(4)));
typedef unsigned short ushort_t;
typedef unsigned int   uint_t;

#define MFMA(a, b, c) __builtin_amdgcn_mfma_f32_16x16x32_bf16((a), (b), (c), 0, 0, 0)

__device__ __forceinline__ ushort_t f2b(float f) {
    uint_t u = __builtin_bit_cast(uint_t, f);
    uint_t r = (u + 0x7FFFu + ((u >> 16) & 1u)) >> 16;   // RTNE
    return (ushort_t)r;
}
__device__ __forceinline__ float b2f(ushort_t u) {
    uint_t v = ((uint_t)u) << 16;
    return __builtin_bit_cast(float, v);
}
__device__ __forceinline__ uint_t pk2(float a, float b) {
    return (uint_t)f2b(a) | ((uint_t)f2b(b) << 16);
}
__device__ __forceinline__ bf16x8 u4b8(uint4 u) {
    return __builtin_bit_cast(bf16x8, u);
}

// ---------------- kernel 1: per-cell winning edge (last write wins) -------
__global__ void edge_win_kernel(const int* __restrict__ ei, int E, int nb,
                                int* __restrict__ win) {
    int e = blockIdx.x * blockDim.x + threadIdx.x;
    if (e >= E) return;
    int r = ei[e];
    int c = ei[E + e];
    int br = r >> 5, bc = c >> 5;
    if (br == bc && br < nb) {
        atomicMax(&win[br * (BSZ * BSZ) + (r & 31) * BSZ + (c & 31)], e);
    }
}

// ---------------- kernel 1b: winning edges scatter their features ---------
// cellinfo[cell] = 4 bf16 {dx,dy,dz,val}; non-winners stay 0xFFFF (NaN).
__global__ void edge_feat_kernel(const int* __restrict__ ei,
                                 const float* __restrict__ ev,
                                 const float* __restrict__ pos,
                                 const int* __restrict__ win, int E,
                                 ushort_t* __restrict__ cellinfo) {
    int e = blockIdx.x * blockDim.x + threadIdx.x;
    if (e >= E) return;
    int r = ei[e];
    int c = ei[E + e];
    int br = r >> 5, bc = c >> 5;
    if (br != bc) return;
    int cell = br * 1024 + (r & 31) * 32 + (c & 31);
    if (win[cell] != e) return;
    float d0 = pos[c * 3 + 0] - pos[r * 3 + 0];
    float d1 = pos[c * 3 + 1] - pos[r * 3 + 1];
    float d2 = pos[c * 3 + 2] - pos[r * 3 + 2];
    float d3 = ev[e];
    uint2 w; w.x = pk2(d0, d1); w.y = pk2(d2, d3);
    *(uint2*)&cellinfo[(size_t)cell * 4] = w;
}

// ---------------- kernel 2: weights -> bf16 MFMA-fragment layout ----------
// dst[((tile*8+ks)*64+lane)*8 + e] = src[(tile*16 + (lane&15))*256
//                                       + ks*32 + (lane>>4)*8 + e]
// One layout serves both A-frags (swapped GEMMs) and B-frags (non-swapped):
// per-lane indexing is identical (l15 = M/N index, lg*8 = K offset).
__global__ void wconv_kernel(const float* __restrict__ qkv_w,
                             const float* __restrict__ proj_w,
                             ushort_t* __restrict__ qkv_wf,
                             ushort_t* __restrict__ proj_wf) {
    int i = blockIdx.x * blockDim.x + threadIdx.x;   // (tile,ks,lane)
    int lane = i & 63, ks = (i >> 6) & 7, tile = i >> 9;
    int l15 = lane & 15, lg = lane >> 4;
    if (tile < 48) {
        const float* src = qkv_w + (size_t)(tile * 16 + l15) * 256 + ks * 32 + lg * 8;
        ushort_t* dst = qkv_wf + (size_t)i * 8;
        #pragma unroll
        for (int e = 0; e < 8; ++e) dst[e] = f2b(src[e]);
    }
    if (tile < 16) {
        const float* src = proj_w + (size_t)(tile * 16 + l15) * 256 + ks * 32 + lg * 8;
        ushort_t* dst = proj_wf + (size_t)i * 8;
        #pragma unroll
        for (int e = 0; e < 8; ++e) dst[e] = f2b(src[e]);
    }
}

// ---------------- kernel 3: qkv GEMM, BM=128 (4 leaf blocks) --------------
// q,k -> leaf-chunked fragment layout in d_out (bf16):
//   addr(ushort) = g*16384 + lc*256 + lane*4,  lc = tt*2 + (row>>4)
// v -> vT[g][ch][32] via non-swapped MFMA orientation.
// No mean rows: kj=32 handled algebraically in leaf_attn.
__global__ __launch_bounds__(256, 2)
void qkv_gemm(const float* __restrict__ x,
              const ushort_t* __restrict__ wf,
              const float* __restrict__ bias,
              ushort_t* qk,
              ushort_t* __restrict__ vT)
{
    __shared__ ushort_t xb[128 * 256];   // 64 KiB
    const int t = threadIdx.x;
    const int wid = t >> 6, lane = t & 63, l15 = lane & 15, lg = lane >> 4;
    const int bi = blockIdx.x, mbase = bi * 128;

    // stage x tile -> bf16 LDS (coalesced)
    #pragma unroll 8
    for (int i = 0; i < 32; ++i) {
        int flat = i * 1024 + t * 4;
        int r = flat >> 8, c = flat & 255;
        float4 xv = *(const float4*)&x[(size_t)(mbase + r) * CH + c];
        uint2 w; w.x = pk2(xv.x, xv.y); w.y = pk2(xv.z, xv.w);
        *(uint2*)&xb[r * 256 + (c ^ ((r & 7) << 3))] = w;
    }
    __syncthreads();

    const int slB = (l15 & 7) << 3;
    for (int mt = 0; mt < 12; ++mt) {
        int tt = wid * 12 + mt;              // ch-tile 0..47
        // fragment-layout weight loads: 1 KB contiguous per wave-instruction
        const ushort_t* wrow = wf + (size_t)tt * 4096 + lane * 8;
        bf16x8 wfr[8];
        #pragma unroll
        for (int ks = 0; ks < 8; ++ks)
            wfr[ks] = *(const bf16x8*)(wrow + ks * 512);
        f32x4 acc[8];
        #pragma unroll
        for (int m = 0; m < 8; ++m) acc[m] = (f32x4){0.f, 0.f, 0.f, 0.f};

        if (tt < 32) {
            // q/k: swapped (A=W, B=x) -> D[ch][row]
            #pragma unroll
            for (int ks = 0; ks < 8; ++ks) {
                int k0 = (ks * 32 + lg * 8) ^ slB;
                #pragma unroll
                for (int m = 0; m < 8; ++m) {
                    bf16x8 xf = *(const bf16x8*)&xb[(m * 16 + l15) * 256 + k0];
                    acc[m] = MFMA(wfr[ks], xf, acc[m]);
                }
            }
            f32x4 bv4 = *(const f32x4*)&bias[tt * 16 + lg * 4];
            #pragma unroll
            for (int m = 0; m < 8; ++m) {
                f32x4 v = acc[m] + bv4;
                uint2 w; w.x = pk2(v[0], v[1]); w.y = pk2(v[2], v[3]);
                int g = bi * 4 + (m >> 1), lc = tt * 2 + (m & 1);
                *(uint2*)&qk[(size_t)g * 16384 + lc * 256 + lane * 4] = w;
            }
        } else {
            // v: non-swapped (A=x, B=W) -> D[row][ch] (transposed frag)
            #pragma unroll
            for (int ks = 0; ks < 8; ++ks) {
                int k0 = (ks * 32 + lg * 8) ^ slB;
                #pragma unroll
                for (int m = 0; m < 8; ++m) {
                    bf16x8 xf = *(const bf16x8*)&xb[(m * 16 + l15) * 256 + k0];
                    acc[m] = MFMA(xf, wfr[ks], acc[m]);
                }
            }
            int vch = (tt - 32) * 16 + l15;
            float bv = bias[512 + vch];
            #pragma unroll
            for (int m = 0; m < 8; ++m) {
                f32x4 v = acc[m];
                uint2 w; w.x = pk2(v[0] + bv, v[1] + bv);
                w.y = pk2(v[2] + bv, v[3] + bv);
                int g = bi * 4 + (m >> 1);
                *(uint2*)&vT[(size_t)g * 8192 + vch * 32 + (m & 1) * 16 + lg * 4] = w;
            }
        }
    }
}

// ---------------- kernel 4: attention + proj per leaf block ---------------
// LDS 24,576 B -> 6 blocks/CU. One barrier (before proj).
// kj=32 column: s2 = mean of the 32 raw scores (exact: k row32 = mean of k
// rows incl bias); its PV term folds into comb (+= comb32/32, exact vs
// v-mean by linearity of the MFMA sum).
#define L_XO     0        // bf16 [32 qi][256 c swz]             16384 B
#define L_COMB   16384    // bf16 [4h][32 qi][32 kj swz]          8192 B
#define L_TOTAL  24576

__global__ __launch_bounds__(256, 6)
void leaf_attn(const ushort_t* qk,            // aliases out (bf16 view)
               const ushort_t* __restrict__ vT,
               const ushort_t* __restrict__ cellinfo,
               const ushort_t* __restrict__ proj_wf,
               const float* __restrict__ proj_b,
               const float* __restrict__ gate_w,
               const float* __restrict__ gate_b,
               float* out)
{
    __shared__ __align__(16) char smem[L_TOTAL];
    ushort_t* xo   = (ushort_t*)(smem + L_XO);
    ushort_t* comb = (ushort_t*)(smem + L_COMB);

    const int b = blockIdx.x, t = threadIdx.x;
    const int h = t >> 6, lane = t & 63, l15 = lane & 15, lg = lane >> 4;
    const int base = b * BSZ;
    const ushort_t* qkb = qk + (size_t)b * 16384;

    // ---- direct fragment loads (all coalesced / L2-friendly) ------------
    uint4 qld[2][2], kld[2][2];              // [row-tile][ks]
    #pragma unroll
    for (int rt = 0; rt < 2; ++rt) {
        #pragma unroll
        for (int ks = 0; ks < 2; ++ks) {
            int ttq = h * 4 + ks * 2 + (lg >> 1);
            int a0 = (ttq * 2 + rt) * 256 + ((lg & 1) * 32 + l15) * 4;
            uint2 u0 = *(const uint2*)&qkb[a0];
            uint2 u1 = *(const uint2*)&qkb[a0 + 64];
            qld[rt][ks] = (uint4){u0.x, u0.y, u1.x, u1.y};
            int b0 = ((ttq + 16) * 2 + rt) * 256 + ((lg & 1) * 32 + l15) * 4;
            uint2 w0 = *(const uint2*)&qkb[b0];
            uint2 w1 = *(const uint2*)&qkb[b0 + 64];
            kld[rt][ks] = (uint4){w0.x, w0.y, w1.x, w1.y};
        }
    }
    bf16x8 vf[4];                            // PV A-frags (vT direct)
    #pragma unroll
    for (int ct = 0; ct < 4; ++ct)
        vf[ct] = *(const bf16x8*)&vT[(size_t)b * 8192
                                     + (h * 64 + ct * 16 + l15) * 32 + lg * 8];
    const float gw0 = gate_w[h * 4 + 0], gw1 = gate_w[h * 4 + 1];
    const float gw2 = gate_w[h * 4 + 2], gw3 = gate_w[h * 4 + 3];
    const float gb  = gate_b[h];

    // ---- scores MFMA: A=k (M=kj), B=q (N=qi) -> D[kj][qi] ---------------
    f32x4 s[2][2];
    #pragma unroll
    for (int qt = 0; qt < 2; ++qt) {
        s[qt][0] = (f32x4){0.f,0.f,0.f,0.f};
        s[qt][1] = (f32x4){0.f,0.f,0.f,0.f};
    }
    #pragma unroll
    for (int qt = 0; qt < 2; ++qt) {
        #pragma unroll
        for (int ks = 0; ks < 2; ++ks) {
            bf16x8 qf = u4b8(qld[qt][ks]);
            #pragma unroll
            for (int kt = 0; kt < 2; ++kt)
                s[qt][kt] = MFMA(u4b8(kld[kt][ks]), qf, s[qt][kt]);
        }
    }

    // ---- softmax + gate in-register via cellinfo fragments --------------
    const ushort_t* crow = cellinfo + (size_t)b * 4096;   // 1024 cells * 4
    #pragma unroll
    for (int qt = 0; qt < 2; ++qt) {
        int qi = qt * 16 + l15;
        float r[8], gt[8];
        float rawsum = 0.f;
        #pragma unroll
        for (int kt = 0; kt < 2; ++kt) {
            int kj0 = kt * 16 + lg * 4;
            const uint_t* cp = (const uint_t*)(crow + ((size_t)qi * 32 + kj0) * 4);
            uint4 cA = *(const uint4*)cp;        // cells j=0,1
            uint4 cB = *(const uint4*)(cp + 4);  // cells j=2,3
            uint_t d01[4] = {cA.x, cA.z, cB.x, cB.z};
            uint_t d23[4] = {cA.y, cA.w, cB.y, cB.w};
            #pragma unroll
            for (int j = 0; j < 4; ++j) {
                int kj = kj0 + j;
                bool fixed = (kj == qi);
                ushort_t e3b = (ushort_t)(d23[j] >> 16);
                bool valid = (e3b != (ushort_t)0xFFFFu);
                float e3 = b2f(e3b);
                float sb = fixed ? 1.0f : (valid ? e3 : -INFINITY);
                float g;
                if (fixed)      g = gw3 + gb;
                else if (valid) g = b2f((ushort_t)(d01[j] & 0xFFFF)) * gw0
                                  + b2f((ushort_t)(d01[j] >> 16))    * gw1
                                  + b2f((ushort_t)(d23[j] & 0xFFFF)) * gw2
                                  + e3 * gw3 + gb;
                else            g = 0.0f;
                float sraw = s[qt][kt][j];
                rawsum += sraw;
                r[kt * 4 + j]  = sraw * 0.125f + sb;
                gt[kt * 4 + j] = g;
            }
        }
        // kj=32 score from the mean of the 32 raw scores (exact linearity)
        rawsum += __shfl_xor(rawsum, 16);
        rawsum += __shfl_xor(rawsum, 32);
        float r2 = rawsum * (0.125f / 32.0f) + 1.0f;   // uniform across lanes

        float m = fmaxf(fmaxf(fmaxf(r[0], r[1]), fmaxf(r[2], r[3])),
                        fmaxf(fmaxf(r[4], r[5]), fmaxf(r[6], r[7])));
        m = fmaxf(m, r2);
        m = fmaxf(m, __shfl_xor(m, 16));
        m = fmaxf(m, __shfl_xor(m, 32));
        float sum = 0.f;
        #pragma unroll
        for (int i = 0; i < 8; ++i) { r[i] = __expf(r[i] - m); sum += r[i]; }
        sum += __shfl_xor(sum, 16);
        sum += __shfl_xor(sum, 32);
        float e2 = __expf(r2 - m);                     // uniform
        float inv = 1.0f / (sum + e2);
        // fold the kj=32 PV contribution: comb32 * v_mean == sum_kj
        // (comb32/32)*v[kj]  ->  add comb32/32 to every comb entry
        float comb32 = e2 * inv + (gw3 + gb);
        float cadd = comb32 * 0.03125f;
        int swz = (l15 >> 2) << 3;
        #pragma unroll
        for (int kt = 0; kt < 2; ++kt) {
            int kj0 = kt * 16 + lg * 4;
            uint2 w;
            w.x = pk2(r[kt*4+0] * inv + gt[kt*4+0] + cadd,
                      r[kt*4+1] * inv + gt[kt*4+1] + cadd);
            w.y = pk2(r[kt*4+2] * inv + gt[kt*4+2] + cadd,
                      r[kt*4+3] * inv + gt[kt*4+3] + cadd);
            *(uint2*)&comb[(h * 32 + qi) * 32 + (kj0 ^ swz)] = w;
        }
    }
    // comb is wave-private (head h) -> no __syncthreads needed.

    // ---- PV MFMA: A=vT (M=c), B=comb (N=qi) -> D[c][qi] -----------------
    bf16x8 cfr[2];
    #pragma unroll
    for (int qt = 0; qt < 2; ++qt) {
        int qi = qt * 16 + l15;
        int off = (lg * 8) ^ (((l15 >> 2) & 3) << 3);
        cfr[qt] = *(const bf16x8*)&comb[(h * 32 + qi) * 32 + off];
    }
    #pragma unroll
    for (int ct = 0; ct < 4; ++ct) {
        #pragma unroll
        for (int qt = 0; qt < 2; ++qt) {
            f32x4 acc = {0.f, 0.f, 0.f, 0.f};
            acc = MFMA(vf[ct], cfr[qt], acc);
            int qi = qt * 16 + l15;
            uint2 w;
            w.x = pk2(acc[0], acc[1]);
            w.y = pk2(acc[2], acc[3]);
            int c0 = h * 64 + ct * 16 + lg * 4;
            *(uint2*)&xo[qi * 256 + (c0 ^ ((l15 & 7) << 3))] = w;
        }
    }
    __syncthreads();   // the only barrier: xo is read cross-wave by proj

    // ---- proj MFMA (swapped, fragment-layout weights) + fp32 store ------
    {
        const int slR = (l15 & 7) << 3;
        #pragma unroll
        for (int mt = 0; mt < 4; ++mt) {
            int pt = h * 4 + mt;                 // proj ch-tile 0..15
            int n0 = pt * 16;
            const ushort_t* wrow = proj_wf + (size_t)pt * 4096 + lane * 8;
            f32x4 acc0 = {0.f, 0.f, 0.f, 0.f};
            f32x4 acc1 = {0.f, 0.f, 0.f, 0.f};
            #pragma unroll
            for (int ks = 0; ks < 8; ++ks) {
                bf16x8 a = *(const bf16x8*)(wrow + ks * 512);
                int k0 = ks * 32 + lg * 8;
                bf16x8 b0 = *(const bf16x8*)&xo[l15 * 256 + (k0 ^ slR)];
                bf16x8 b1 = *(const bf16x8*)&xo[(16 + l15) * 256 + (k0 ^ slR)];
                acc0 = MFMA(a, b0, acc0);
                acc1 = MFMA(a, b1, acc1);
            }
            f32x4 bv = *(const f32x4*)(proj_b + n0 + lg * 4);
            acc0 += bv; acc1 += bv;
            int c0 = n0 + lg * 4;
            *(f32x4*)(out + (size_t)(base + l15) * 256 + c0)      = acc0;
            *(f32x4*)(out + (size_t)(base + 16 + l15) * 256 + c0) = acc1;
        }
    }
}

extern "C" void kernel_launch(void* const* d_in, const int* in_sizes, int n_in,
                              void* d_out, int out_size, void* d_ws, size_t ws_size,
                              hipStream_t stream) {
    const float* x      = (const float*)d_in[0];
    const int*   ei     = (const int*)  d_in[1];
    const float* ev     = (const float*)d_in[2];
    const float* pos    = (const float*)d_in[3];
    const float* qkv_w  = (const float*)d_in[4];
    const float* qkv_b  = (const float*)d_in[5];
    const float* proj_w = (const float*)d_in[6];
    const float* proj_b = (const float*)d_in[7];
    const float* gate_w = (const float*)d_in[8];
    const float* gate_b = (const float*)d_in[9];
    float* out = (float*)d_out;

    const int E  = in_sizes[2];
    const int N  = in_sizes[0] / CH;
    const int nb = N / BSZ;

    char* ws = (char*)d_ws;
    int*      win      = (int*)ws;                              // nb*4096 B
    ushort_t* cellinfo = (ushort_t*)(ws + (size_t)nb * 4096);   // nb*8192 B
    size_t off = (size_t)nb * 12288;
    ushort_t* qkv_wf  = (ushort_t*)(ws + off); off += 48 * 8 * 64 * 8 * 2;
    ushort_t* proj_wf = (ushort_t*)(ws + off); off += 16 * 8 * 64 * 8 * 2;
    ushort_t* vT      = (ushort_t*)(ws + off); off += (size_t)nb * 16384;
    ushort_t* qk      = (ushort_t*)d_out;               // d_out as bf16 scratch

    // one memset covers win (-1) and cellinfo (NaN sentinel) — both 0xFF
    hipMemsetAsync(ws, 0xFF, (size_t)nb * 12288, stream);
    edge_win_kernel<<<(E + 255) / 256, 256, 0, stream>>>(ei, E, nb, win);
    edge_feat_kernel<<<(E + 255) / 256, 256, 0, stream>>>(ei, ev, pos, win, E,
                                                          cellinfo);
    wconv_kernel<<<96, 256, 0, stream>>>(qkv_w, proj_w, qkv_wf, proj_wf);
    qkv_gemm<<<nb / 4, 256, 0, stream>>>(x, qkv_wf, qkv_b, qk, vT);
    leaf_attn<<<nb, 256, 0, stream>>>(qk, vT, cellinfo,
                                      proj_wf, proj_b, gate_w, gate_b, out);
}

// Round 7
// 287.863 us; speedup vs baseline: 1.2450x; 1.1456x over previous
//
#include <hip/hip_runtime.h>
#include <math.h>

#define BSZ 32
#define CH  256

typedef short  bf16x8 __attribute__((ext_vector_type(8)));
typedef float  f32x4  __attribute__((ext_vector_type(4)));
typedef unsigned short ushort_t;
typedef unsigned int   uint_t;

#define MFMA(a, b, c) __builtin_amdgcn_mfma_f32_16x16x32_bf16((a), (b), (c), 0, 0, 0)

__device__ __forceinline__ ushort_t f2b(float f) {
    uint_t u = __builtin_bit_cast(uint_t, f);
    uint_t r = (u + 0x7FFFu + ((u >> 16) & 1u)) >> 16;   // RTNE
    return (ushort_t)r;
}
__device__ __forceinline__ float b2f(ushort_t u) {
    uint_t v = ((uint_t)u) << 16;
    return __builtin_bit_cast(float, v);
}
__device__ __forceinline__ uint_t pk2(float a, float b) {
    return (uint_t)f2b(a) | ((uint_t)f2b(b) << 16);
}
__device__ __forceinline__ bf16x8 u4b8(uint4 u) {
    return __builtin_bit_cast(bf16x8, u);
}

// ---------------- kernel 1: per-cell winning edge (last write wins) -------
__global__ void edge_win_kernel(const int* __restrict__ ei, int E, int nb,
                                int* __restrict__ win) {
    int e = blockIdx.x * blockDim.x + threadIdx.x;
    if (e >= E) return;
    int r = ei[e];
    int c = ei[E + e];
    int br = r >> 5, bc = c >> 5;
    if (br == bc && br < nb) {
        atomicMax(&win[br * (BSZ * BSZ) + (r & 31) * BSZ + (c & 31)], e);
    }
}

// ---------------- kernel 1b: winning edges scatter their features ---------
// cellinfo[cell] = 4 bf16 {dx,dy,dz,val}; non-winners stay 0xFFFF (NaN).
__global__ void edge_feat_kernel(const int* __restrict__ ei,
                                 const float* __restrict__ ev,
                                 const float* __restrict__ pos,
                                 const int* __restrict__ win, int E,
                                 ushort_t* __restrict__ cellinfo) {
    int e = blockIdx.x * blockDim.x + threadIdx.x;
    if (e >= E) return;
    int r = ei[e];
    int c = ei[E + e];
    int br = r >> 5, bc = c >> 5;
    if (br != bc) return;
    int cell = br * 1024 + (r & 31) * 32 + (c & 31);
    if (win[cell] != e) return;
    float d0 = pos[c * 3 + 0] - pos[r * 3 + 0];
    float d1 = pos[c * 3 + 1] - pos[r * 3 + 1];
    float d2 = pos[c * 3 + 2] - pos[r * 3 + 2];
    float d3 = ev[e];
    uint2 w; w.x = pk2(d0, d1); w.y = pk2(d2, d3);
    *(uint2*)&cellinfo[(size_t)cell * 4] = w;
}

// ---------------- kernel 2: weights -> bf16 MFMA-fragment layout ----------
// dst[((tile*8+ks)*64+lane)*8 + e] = src[(tile*16 + (lane&15))*256
//                                       + ks*32 + (lane>>4)*8 + e]
__global__ void wconv_kernel(const float* __restrict__ qkv_w,
                             const float* __restrict__ proj_w,
                             ushort_t* __restrict__ qkv_wf,
                             ushort_t* __restrict__ proj_wf) {
    int i = blockIdx.x * blockDim.x + threadIdx.x;   // (tile,ks,lane)
    int lane = i & 63, ks = (i >> 6) & 7, tile = i >> 9;
    int l15 = lane & 15, lg = lane >> 4;
    if (tile < 48) {
        const float* src = qkv_w + (size_t)(tile * 16 + l15) * 256 + ks * 32 + lg * 8;
        ushort_t* dst = qkv_wf + (size_t)i * 8;
        #pragma unroll
        for (int e = 0; e < 8; ++e) dst[e] = f2b(src[e]);
    }
    if (tile < 16) {
        const float* src = proj_w + (size_t)(tile * 16 + l15) * 256 + ks * 32 + lg * 8;
        ushort_t* dst = proj_wf + (size_t)i * 8;
        #pragma unroll
        for (int e = 0; e < 8; ++e) dst[e] = f2b(src[e]);
    }
}

// ---------------- fused kernel: qkv GEMM + attention + proj ---------------
// One workgroup = 2 leaf blocks (64 rows), 512 threads (8 waves).
// LDS map (128 KiB -> 1 block/CU):
//   [0      ,  32768) xb  bf16[64][256] swz8   -> comb overlay (16 KiB)
//   [32768  ,  65536) qs  chunk-frag [2][8192] -> xo overlay
//   [65536  ,  98304) ksm chunk-frag [2][8192]
//   [98304  , 131072) vs  vT [2][256ch][32row]
#define LS_XB   0
#define LS_QS   32768
#define LS_KS   65536
#define LS_VS   98304
#define LS_TOT  131072

__global__ __launch_bounds__(512, 2)
void fused_attn(const float* __restrict__ x,
                const ushort_t* __restrict__ qkv_wf,
                const float* __restrict__ qkv_b,
                const ushort_t* __restrict__ cellinfo,
                const ushort_t* __restrict__ proj_wf,
                const float* __restrict__ proj_b,
                const float* __restrict__ gate_w,
                const float* __restrict__ gate_b,
                float* __restrict__ out)
{
    __shared__ __align__(16) char smem[LS_TOT];
    ushort_t* xb   = (ushort_t*)(smem + LS_XB);
    ushort_t* comb = (ushort_t*)(smem + LS_XB);   // overlay (xb dead post-GEMM)
    ushort_t* qs   = (ushort_t*)(smem + LS_QS);
    ushort_t* xo   = (ushort_t*)(smem + LS_QS);   // overlay (q dead post-scores)
    ushort_t* ksm  = (ushort_t*)(smem + LS_KS);
    ushort_t* vs   = (ushort_t*)(smem + LS_VS);

    const int t = threadIdx.x;
    const int w = t >> 6, lane = t & 63, l15 = lane & 15, lg = lane >> 4;
    const int bi = blockIdx.x;
    const int mbase = bi * 64;

    // ---- phase 1: stage x -> bf16 LDS (swz8) ----------------------------
    #pragma unroll
    for (int i = 0; i < 8; ++i) {
        int flat = i * 2048 + t * 4;
        int r = flat >> 8, c = flat & 255;
        float4 xv = *(const float4*)&x[(size_t)(mbase + r) * CH + c];
        uint2 wv; wv.x = pk2(xv.x, xv.y); wv.y = pk2(xv.z, xv.w);
        *(uint2*)&xb[r * 256 + (c ^ ((r & 7) << 3))] = wv;
    }
    __syncthreads();

    // ---- phase 2: qkv GEMM (wave w: tiles it*8+w; it 0,1=q 2,3=k 4,5=v) -
    {
        const int slB = (l15 & 7) << 3;
        f32x4 acc[6][4];
        #pragma unroll
        for (int it = 0; it < 6; ++it)
            #pragma unroll
            for (int m = 0; m < 4; ++m) acc[it][m] = (f32x4){0.f, 0.f, 0.f, 0.f};

        #pragma unroll
        for (int ks = 0; ks < 8; ++ks) {
            int k0 = (ks * 32 + lg * 8) ^ slB;
            bf16x8 xf0 = *(const bf16x8*)&xb[(0 * 16 + l15) * 256 + k0];
            bf16x8 xf1 = *(const bf16x8*)&xb[(1 * 16 + l15) * 256 + k0];
            bf16x8 xf2 = *(const bf16x8*)&xb[(2 * 16 + l15) * 256 + k0];
            bf16x8 xf3 = *(const bf16x8*)&xb[(3 * 16 + l15) * 256 + k0];
            #pragma unroll
            for (int it = 0; it < 6; ++it) {
                int tt = it * 8 + w;
                bf16x8 wf = *(const bf16x8*)(qkv_wf
                               + ((size_t)(tt * 8 + ks)) * 512 + lane * 8);
                if (it < 4) {           // q/k: swapped -> D[ch][row]
                    acc[it][0] = MFMA(wf, xf0, acc[it][0]);
                    acc[it][1] = MFMA(wf, xf1, acc[it][1]);
                    acc[it][2] = MFMA(wf, xf2, acc[it][2]);
                    acc[it][3] = MFMA(wf, xf3, acc[it][3]);
                } else {                // v: non-swapped -> D[row][ch]
                    acc[it][0] = MFMA(xf0, wf, acc[it][0]);
                    acc[it][1] = MFMA(xf1, wf, acc[it][1]);
                    acc[it][2] = MFMA(xf2, wf, acc[it][2]);
                    acc[it][3] = MFMA(xf3, wf, acc[it][3]);
                }
            }
        }
        // stores to LDS (same addressing as the proven global layouts)
        #pragma unroll
        for (int it = 0; it < 6; ++it) {
            int tt = it * 8 + w;
            if (it < 4) {
                f32x4 bv4 = *(const f32x4*)&qkv_b[tt * 16 + lg * 4];
                ushort_t* dst = (it < 2) ? qs : ksm;
                int tloc = (it < 2) ? tt : tt - 16;
                #pragma unroll
                for (int m = 0; m < 4; ++m) {
                    f32x4 v = acc[it][m] + bv4;
                    uint2 wv; wv.x = pk2(v[0], v[1]); wv.y = pk2(v[2], v[3]);
                    int g = m >> 1;
                    *(uint2*)&dst[g * 8192 + (tloc * 2 + (m & 1)) * 256 + lane * 4] = wv;
                }
            } else {
                int vch = (tt - 32) * 16 + l15;
                float bv = qkv_b[512 + vch];
                #pragma unroll
                for (int m = 0; m < 4; ++m) {
                    f32x4 v = acc[it][m];
                    uint2 wv; wv.x = pk2(v[0] + bv, v[1] + bv);
                    wv.y = pk2(v[2] + bv, v[3] + bv);
                    int g = m >> 1;
                    *(uint2*)&vs[g * 8192 + vch * 32 + (m & 1) * 16 + lg * 4] = wv;
                }
            }
        }
    }
    __syncthreads();

    // ---- phase 3: attention (wave: leaf gl = w>>2, head h = w&3) --------
    const int gl = w >> 2, h = w & 3;

    uint4 qld[2][2], kld[2][2];
    #pragma unroll
    for (int rt = 0; rt < 2; ++rt) {
        #pragma unroll
        for (int ks2 = 0; ks2 < 2; ++ks2) {
            int ttq = h * 4 + ks2 * 2 + (lg >> 1);
            int a0 = gl * 8192 + (ttq * 2 + rt) * 256 + ((lg & 1) * 32 + l15) * 4;
            uint2 u0 = *(const uint2*)&qs[a0];
            uint2 u1 = *(const uint2*)&qs[a0 + 64];
            qld[rt][ks2] = (uint4){u0.x, u0.y, u1.x, u1.y};
            uint2 w0 = *(const uint2*)&ksm[a0];
            uint2 w1 = *(const uint2*)&ksm[a0 + 64];
            kld[rt][ks2] = (uint4){w0.x, w0.y, w1.x, w1.y};
        }
    }
    bf16x8 vf[4];
    #pragma unroll
    for (int ct = 0; ct < 4; ++ct)
        vf[ct] = *(const bf16x8*)&vs[gl * 8192 + (h * 64 + ct * 16 + l15) * 32 + lg * 8];

    // preload cellinfo fragments (global; hide latency before barrier)
    const ushort_t* crow = cellinfo + (size_t)(bi * 2 + gl) * 4096;
    uint4 cellA[2][2], cellB[2][2];
    #pragma unroll
    for (int qt = 0; qt < 2; ++qt) {
        int qi = qt * 16 + l15;
        #pragma unroll
        for (int kt = 0; kt < 2; ++kt) {
            int kj0 = kt * 16 + lg * 4;
            const uint_t* cp = (const uint_t*)(crow + ((size_t)qi * 32 + kj0) * 4);
            cellA[qt][kt] = *(const uint4*)cp;
            cellB[qt][kt] = *(const uint4*)(cp + 4);
        }
    }
    const float gw0 = gate_w[h * 4 + 0], gw1 = gate_w[h * 4 + 1];
    const float gw2 = gate_w[h * 4 + 2], gw3 = gate_w[h * 4 + 3];
    const float gb  = gate_b[h];

    __syncthreads();   // all qs reads done before xo overlay writes

    // scores MFMA: A=k (M=kj), B=q (N=qi) -> D[kj][qi]
    f32x4 s[2][2];
    #pragma unroll
    for (int qt = 0; qt < 2; ++qt) {
        s[qt][0] = (f32x4){0.f, 0.f, 0.f, 0.f};
        s[qt][1] = (f32x4){0.f, 0.f, 0.f, 0.f};
    }
    #pragma unroll
    for (int qt = 0; qt < 2; ++qt) {
        #pragma unroll
        for (int ks2 = 0; ks2 < 2; ++ks2) {
            bf16x8 qf = u4b8(qld[qt][ks2]);
            #pragma unroll
            for (int kt = 0; kt < 2; ++kt)
                s[qt][kt] = MFMA(u4b8(kld[kt][ks2]), qf, s[qt][kt]);
        }
    }

    // softmax + gate in-register; kj=32 from mean of raw scores (linearity)
    #pragma unroll
    for (int qt = 0; qt < 2; ++qt) {
        int qi = qt * 16 + l15;
        float r[8], gt[8];
        float rawsum = 0.f;
        #pragma unroll
        for (int kt = 0; kt < 2; ++kt) {
            int kj0 = kt * 16 + lg * 4;
            uint4 cA = cellA[qt][kt], cB = cellB[qt][kt];
            uint_t d01[4] = {cA.x, cA.z, cB.x, cB.z};
            uint_t d23[4] = {cA.y, cA.w, cB.y, cB.w};
            #pragma unroll
            for (int j = 0; j < 4; ++j) {
                int kj = kj0 + j;
                bool fixed = (kj == qi);
                ushort_t e3b = (ushort_t)(d23[j] >> 16);
                bool valid = (e3b != (ushort_t)0xFFFFu);
                float e3 = b2f(e3b);
                float sb = fixed ? 1.0f : (valid ? e3 : -INFINITY);
                float g;
                if (fixed)      g = gw3 + gb;
                else if (valid) g = b2f((ushort_t)(d01[j] & 0xFFFF)) * gw0
                                  + b2f((ushort_t)(d01[j] >> 16))    * gw1
                                  + b2f((ushort_t)(d23[j] & 0xFFFF)) * gw2
                                  + e3 * gw3 + gb;
                else            g = 0.0f;
                float sraw = s[qt][kt][j];
                rawsum += sraw;
                r[kt * 4 + j]  = sraw * 0.125f + sb;
                gt[kt * 4 + j] = g;
            }
        }
        rawsum += __shfl_xor(rawsum, 16);
        rawsum += __shfl_xor(rawsum, 32);
        float r2 = rawsum * (0.125f / 32.0f) + 1.0f;

        float m = fmaxf(fmaxf(fmaxf(r[0], r[1]), fmaxf(r[2], r[3])),
                        fmaxf(fmaxf(r[4], r[5]), fmaxf(r[6], r[7])));
        m = fmaxf(m, r2);
        m = fmaxf(m, __shfl_xor(m, 16));
        m = fmaxf(m, __shfl_xor(m, 32));
        float sum = 0.f;
        #pragma unroll
        for (int i = 0; i < 8; ++i) { r[i] = __expf(r[i] - m); sum += r[i]; }
        sum += __shfl_xor(sum, 16);
        sum += __shfl_xor(sum, 32);
        float e2 = __expf(r2 - m);
        float inv = 1.0f / (sum + e2);
        float comb32 = e2 * inv + (gw3 + gb);
        float cadd = comb32 * 0.03125f;     // fold kj=32 PV into every entry
        int swz = (l15 >> 2) << 3;
        #pragma unroll
        for (int kt = 0; kt < 2; ++kt) {
            int kj0 = kt * 16 + lg * 4;
            uint2 wv;
            wv.x = pk2(r[kt*4+0] * inv + gt[kt*4+0] + cadd,
                       r[kt*4+1] * inv + gt[kt*4+1] + cadd);
            wv.y = pk2(r[kt*4+2] * inv + gt[kt*4+2] + cadd,
                       r[kt*4+3] * inv + gt[kt*4+3] + cadd);
            *(uint2*)&comb[(gl * 4 + h) * 1024 + qi * 32 + (kj0 ^ swz)] = wv;
        }
    }
    // comb is wave-private -> no barrier

    // PV MFMA: A=vT (M=c), B=comb (N=qi) -> D[c][qi] -> xo (qs overlay)
    bf16x8 cfr[2];
    #pragma unroll
    for (int qt = 0; qt < 2; ++qt) {
        int qi = qt * 16 + l15;
        int off = (lg * 8) ^ (((l15 >> 2) & 3) << 3);
        cfr[qt] = *(const bf16x8*)&comb[(gl * 4 + h) * 1024 + qi * 32 + off];
    }
    #pragma unroll
    for (int ct = 0; ct < 4; ++ct) {
        #pragma unroll
        for (int qt = 0; qt < 2; ++qt) {
            f32x4 acc = {0.f, 0.f, 0.f, 0.f};
            acc = MFMA(vf[ct], cfr[qt], acc);
            int qi = qt * 16 + l15;
            uint2 wv;
            wv.x = pk2(acc[0], acc[1]);
            wv.y = pk2(acc[2], acc[3]);
            int c0 = h * 64 + ct * 16 + lg * 4;
            *(uint2*)&xo[gl * 8192 + qi * 256 + (c0 ^ ((l15 & 7) << 3))] = wv;
        }
    }
    __syncthreads();   // xo read cross-wave by proj

    // ---- phase 4: proj (wave: leaf pl = w>>2, tiles (w&3)+4i) -----------
    {
        const int slR = (l15 & 7) << 3;
        const int pl = w >> 2, pw = w & 3;
        f32x4 pacc[4][2];
        #pragma unroll
        for (int i = 0; i < 4; ++i) {
            pacc[i][0] = (f32x4){0.f, 0.f, 0.f, 0.f};
            pacc[i][1] = (f32x4){0.f, 0.f, 0.f, 0.f};
        }
        #pragma unroll
        for (int ks = 0; ks < 8; ++ks) {
            int k0 = ks * 32 + lg * 8;
            bf16x8 b0 = *(const bf16x8*)&xo[pl * 8192 + l15 * 256 + (k0 ^ slR)];
            bf16x8 b1 = *(const bf16x8*)&xo[pl * 8192 + (16 + l15) * 256 + (k0 ^ slR)];
            #pragma unroll
            for (int i = 0; i < 4; ++i) {
                int pt = pw + i * 4;
                bf16x8 a = *(const bf16x8*)(proj_wf
                              + ((size_t)(pt * 8 + ks)) * 512 + lane * 8);
                pacc[i][0] = MFMA(a, b0, pacc[i][0]);
                pacc[i][1] = MFMA(a, b1, pacc[i][1]);
            }
        }
        #pragma unroll
        for (int i = 0; i < 4; ++i) {
            int pt = pw + i * 4, n0 = pt * 16;
            f32x4 bv = *(const f32x4*)&proj_b[n0 + lg * 4];
            f32x4 o0 = pacc[i][0] + bv;
            f32x4 o1 = pacc[i][1] + bv;
            int c0 = n0 + lg * 4;
            *(f32x4*)&out[(size_t)(mbase + pl * 32 + l15) * 256 + c0]      = o0;
            *(f32x4*)&out[(size_t)(mbase + pl * 32 + 16 + l15) * 256 + c0] = o1;
        }
    }
}

extern "C" void kernel_launch(void* const* d_in, const int* in_sizes, int n_in,
                              void* d_out, int out_size, void* d_ws, size_t ws_size,
                              hipStream_t stream) {
    const float* x      = (const float*)d_in[0];
    const int*   ei     = (const int*)  d_in[1];
    const float* ev     = (const float*)d_in[2];
    const float* pos    = (const float*)d_in[3];
    const float* qkv_w  = (const float*)d_in[4];
    const float* qkv_b  = (const float*)d_in[5];
    const float* proj_w = (const float*)d_in[6];
    const float* proj_b = (const float*)d_in[7];
    const float* gate_w = (const float*)d_in[8];
    const float* gate_b = (const float*)d_in[9];
    float* out = (float*)d_out;

    const int E  = in_sizes[2];
    const int N  = in_sizes[0] / CH;
    const int nb = N / BSZ;

    char* ws = (char*)d_ws;
    int*      win      = (int*)ws;                              // nb*4096 B
    ushort_t* cellinfo = (ushort_t*)(ws + (size_t)nb * 4096);   // nb*8192 B
    size_t off = (size_t)nb * 12288;
    ushort_t* qkv_wf  = (ushort_t*)(ws + off); off += 48 * 8 * 64 * 8 * 2;
    ushort_t* proj_wf = (ushort_t*)(ws + off); off += 16 * 8 * 64 * 8 * 2;

    // one memset covers win (-1) and cellinfo (NaN sentinel) — both 0xFF
    hipMemsetAsync(ws, 0xFF, (size_t)nb * 12288, stream);
    edge_win_kernel<<<(E + 255) / 256, 256, 0, stream>>>(ei, E, nb, win);
    edge_feat_kernel<<<(E + 255) / 256, 256, 0, stream>>>(ei, ev, pos, win, E,
                                                          cellinfo);
    wconv_kernel<<<96, 256, 0, stream>>>(qkv_w, proj_w, qkv_wf, proj_wf);
    fused_attn<<<nb / 2, 512, 0, stream>>>(x, qkv_wf, qkv_b, cellinfo,
                                           proj_wf, proj_b, gate_w, gate_b, out);
}